// Round 1
// baseline (424.856 us; speedup 1.0000x reference)
//
#include <hip/hip_runtime.h>
#include <hip/hip_bf16.h>
#include <stdint.h>

typedef unsigned short u16;
typedef unsigned int   u32;
typedef __attribute__((ext_vector_type(8))) short short8;
typedef __attribute__((ext_vector_type(4))) float floatx4;
typedef __attribute__((ext_vector_type(4))) float f4;

#define NFEAT 256
// weight-pair region boundaries (float2 pairs): Wp 256x256, Wih 768x256, Whh 768x256
#define WPAIRS 229376
#define P_WP   32768
#define P_WIH  131072

__device__ __forceinline__ u16 f2b(float f) {
    u32 x = __builtin_bit_cast(u32, f);
    x += 0x7fffu + ((x >> 16) & 1u);   // round-to-nearest-even
    return (u16)(x >> 16);
}
__device__ __forceinline__ float sigmoidf_(float x) {
    return 1.0f / (1.0f + __expf(-x));
}
__device__ __forceinline__ f4 ldnt4(const float* p) {
    return __builtin_nontemporal_load((const f4*)p);   // nf is streamed once: no L2 alloc
}

// -------- Kernel 1: fused prep + single-pass attention pooling --------
// One block (256 thr = 4 waves) per graph.
//  * segment bounds: redundant per-wave 32-ary lower-bound search (half-wave
//    searches g, half searches g+1); 4 ballot rounds, seg stays L2-hot.
//  * wave 0: graph-uniform logit part (gbase) + gf->bf16 copy
//  * wave 1: this block's 56-float2 slice of the weight bf16 conversion
//  * main loop: quarter-wave (16-lane) row ownership -> 4 shuffle stages
//    reduce 4 rows at once (vs 24 DS ops before); depth-1 row prefetch;
//    no-max softmax (|z| small: 0.05-scale weights).
__global__ void __launch_bounds__(256)
k1_attn_pool(const float* __restrict__ nf, const float* __restrict__ gf,
             const int* __restrict__ seg, int V, int G,
             const float* __restrict__ Wl, const float* __restrict__ bl,
             const float* __restrict__ Wp, const float* __restrict__ Wih,
             const float* __restrict__ Whh,
             u16* __restrict__ s_out, float* __restrict__ pres,
             u16* __restrict__ gfb, u16* __restrict__ wpb,
             u16* __restrict__ wihb, u16* __restrict__ whhb)
{
    const int g    = blockIdx.x;
    const int t    = threadIdx.x;
    const int lane = t & 63;
    const int wv   = t >> 6;
    const int sub  = lane & 15;      // position within quarter
    const int q    = lane >> 4;      // quarter 0..3 (owns one row per iter)

    __shared__ float sh_gbase;
    __shared__ __align__(16) float accs[4][256];
    __shared__ float lws[4];

    // ---- 32-ary dual lower-bound: lanes 0-31 target g, lanes 32-63 target g+1
    const int h = lane >> 5;
    const int target = g + h;
    int S0 = 1;
    while ((long long)S0 * 32 < V) S0 *= 32;     // V=262144 -> 32768,1024,32,1
    int pos = 0;
    for (int step = S0; step >= 1; step /= 32) {
        if (pos < V) {   // per-half uniform; exec-masked ballot is fine
            int idx = pos + (lane & 31) * step + step - 1;
            idx = min(idx, V - 1);               // clamped probes read seg[V-1] (>= t here)
            unsigned long long b = __ballot(seg[idx] < target);
            int cnt = h ? __popcll(b >> 32) : __popcll(b & 0xFFFFFFFFull);
            pos += cnt * step;
        }
    }
    pos = min(pos, V);
    const int start = __shfl(pos, 0);
    const int end_  = __shfl(pos, 32);
    const int count = end_ - start;

    // ---- issue first row prefetch ASAP (before role work / barrier) ----
    const float* rowbase = nf + (size_t)start * NFEAT + sub * 16;
    const int r0 = wv * 4 + q;
    f4 x[4] = {{0,0,0,0},{0,0,0,0},{0,0,0,0},{0,0,0,0}};
    if (r0 < count) {
        const float* p = rowbase + (size_t)r0 * NFEAT;
        #pragma unroll
        for (int j = 0; j < 4; ++j) x[j] = ldnt4(p + j * 4);
    }
    // node-half Wl coefficients: 16 per lane (col slice sub*16..sub*16+15)
    f4 wn[4];
    #pragma unroll
    for (int j = 0; j < 4; ++j) wn[j] = *(const f4*)(Wl + NFEAT + sub * 16 + j * 4);

    // ---- role phase ----
    if (wv == 0) {
        // gbase = relu(gf[g]) . Wl[0:256] + bl ; also gf -> bf16
        f4 gv = *(const f4*)(gf + (size_t)g * NFEAT + lane * 4);
        f4 wl = *(const f4*)(Wl + lane * 4);
        float v = fmaxf(gv[0], 0.f) * wl[0] + fmaxf(gv[1], 0.f) * wl[1]
                + fmaxf(gv[2], 0.f) * wl[2] + fmaxf(gv[3], 0.f) * wl[3];
        #pragma unroll
        for (int o = 32; o > 0; o >>= 1) v += __shfl_xor(v, o);
        if (lane == 0) sh_gbase = v + bl[0];
        uint2 pk;
        pk.x = (u32)f2b(gv[0]) | ((u32)f2b(gv[1]) << 16);
        pk.y = (u32)f2b(gv[2]) | ((u32)f2b(gv[3]) << 16);
        *(uint2*)(gfb + (size_t)g * NFEAT + lane * 4) = pk;
    } else if (wv == 1) {
        // this block's slice of the fp32->bf16 weight conversion
        const int PPB = (WPAIRS + G - 1) / G;    // 56 for G=4096
        for (int pi = lane; pi < PPB; pi += 64) {
            int P = g * PPB + pi;
            if (P < WPAIRS) {
                const float* src; u32* dst; int o;
                if (P < P_WP)       { src = Wp;  dst = (u32*)wpb;  o = P; }
                else if (P < P_WIH) { src = Wih; dst = (u32*)wihb; o = P - P_WP; }
                else                { src = Whh; dst = (u32*)whhb; o = P - P_WIH; }
                float2 v = *(const float2*)(src + (size_t)o * 2);
                dst[o] = (u32)f2b(v.x) | ((u32)f2b(v.y) << 16);
            }
        }
    }
    __syncthreads();
    const float gbase = sh_gbase;

    // ---- main loop: 4 rows/iter/wave, quarter q owns row i+q ----
    float l = 0.f;
    f4 acc[4] = {{0,0,0,0},{0,0,0,0},{0,0,0,0},{0,0,0,0}};
    for (int i = wv * 4; i < count; i += 16) {
        f4 nx[4] = {{0,0,0,0},{0,0,0,0},{0,0,0,0},{0,0,0,0}};
        const int rn = i + 16 + q;
        if (rn < count) {
            const float* p = rowbase + (size_t)rn * NFEAT;
            #pragma unroll
            for (int j = 0; j < 4; ++j) nx[j] = ldnt4(p + j * 4);
        }
        float d = 0.f;
        #pragma unroll
        for (int j = 0; j < 4; ++j)
            d += x[j][0]*wn[j][0] + x[j][1]*wn[j][1]
               + x[j][2]*wn[j][2] + x[j][3]*wn[j][3];
        // reduce the 16 col-partials within the quarter (all 4 rows at once)
        d += __shfl_xor(d, 1);
        d += __shfl_xor(d, 2);
        d += __shfl_xor(d, 4);
        d += __shfl_xor(d, 8);
        float z = d + gbase;
        z = (z > 0.f) ? z : 0.01f * z;                  // leaky_relu 0.01
        float pw = (i + q < count) ? __expf(z) : 0.f;   // invalid row -> 0
        l += pw;
        #pragma unroll
        for (int j = 0; j < 4; ++j) acc[j] += pw * x[j];
        x[0] = nx[0]; x[1] = nx[1]; x[2] = nx[2]; x[3] = nx[3];
    }

    // ---- merge: quarters within wave, then waves via LDS ----
    #pragma unroll
    for (int j = 0; j < 4; ++j) {
        #pragma unroll
        for (int c = 0; c < 4; ++c) {
            float v = acc[j][c];
            v += __shfl_xor(v, 16);
            v += __shfl_xor(v, 32);
            acc[j][c] = v;
        }
    }
    l += __shfl_xor(l, 16);
    l += __shfl_xor(l, 32);
    if (lane < 16) {
        #pragma unroll
        for (int j = 0; j < 4; ++j)
            *(f4*)&accs[wv][sub * 16 + j * 4] = acc[j];
    }
    if (lane == 0) lws[wv] = l;
    __syncthreads();

    const float L   = (lws[0] + lws[1]) + (lws[2] + lws[3]);
    const float sv  = (accs[0][t] + accs[1][t]) + (accs[2][t] + accs[3][t]);
    const float inv = (L > 0.f) ? 1.f / L : 0.f;        // count==0 -> s=0
    s_out[(size_t)g * NFEAT + t] = f2b(sv * inv);
    if (t == 0) pres[g] = (count > 0) ? 1.f : 0.f;
}

// -------- Kernel 2 (fused): context projection + elu + GRU cell --------
// One block per 16-graph stripe (512 thr = 8 waves). Phase A: waves compute
// ctx = elu(s@Wp^T + bp*pres) into LDS (padded stride). Phase B: GRU GEMMs
// with A-fragments (ctx from LDS, gfb from global) loaded once per wave.
#define CTX_LD 264   // 16-row LDS ctx, row stride 264 u16 (528 B) to break banks
__global__ void __launch_bounds__(512)
k2_fused(const u16* __restrict__ s, const u16* __restrict__ wpb,
         const float* __restrict__ bp, const float* __restrict__ pres,
         const u16* __restrict__ gfb, const float* __restrict__ gf,
         const u16* __restrict__ wihb, const u16* __restrict__ whhb,
         const float* __restrict__ bih, const float* __restrict__ bhh,
         float* __restrict__ out)
{
    __shared__ u16 ctx[16][CTX_LD];
    const int t = threadIdx.x;
    const int w = t >> 6;            // wave 0..7
    const int lane = t & 63;
    const int m0 = blockIdx.x * 16;  // graph-row stripe
    const int lr = lane & 15;
    const int kh = lane >> 4;

    // ---- phase A: wave w computes ctx col-tiles {2w, 2w+1} ----
    {
        const short* A = (const short*)s + (size_t)(m0 + lr) * NFEAT + kh * 8;
        short8 af[8];
        #pragma unroll
        for (int kk = 0; kk < 8; ++kk) af[kk] = *(const short8*)(A + kk * 32);

        #pragma unroll
        for (int nt = 0; nt < 2; ++nt) {
            const int n0 = (w * 2 + nt) * 16;
            const short* B = (const short*)wpb + (size_t)(n0 + lr) * NFEAT + kh * 8;
            floatx4 acc = {0.f, 0.f, 0.f, 0.f};
            #pragma unroll
            for (int kk = 0; kk < 8; ++kk)
                acc = __builtin_amdgcn_mfma_f32_16x16x32_bf16(af[kk], *(const short8*)(B + kk * 32), acc, 0, 0, 0);
            const int col = n0 + lr;
            const float bias = bp[col];
            #pragma unroll
            for (int r = 0; r < 4; ++r) {
                int rl = kh * 4 + r;                    // local row
                float x = acc[r] + bias * pres[m0 + rl];
                x = (x > 0.0f) ? x : (__expf(x) - 1.0f);  // elu
                ctx[rl][col] = f2b(x);
            }
        }
    }
    __syncthreads();

    // ---- phase B: wave w handles out col-tiles {2w, 2w+1} ----
    short8 a1[8], a2[8];
    #pragma unroll
    for (int kk = 0; kk < 8; ++kk)
        a1[kk] = *(const short8*)&ctx[lr][kk * 32 + kh * 8];
    {
        const short* A2 = (const short*)gfb + (size_t)(m0 + lr) * NFEAT + kh * 8;
        #pragma unroll
        for (int kk = 0; kk < 8; ++kk) a2[kk] = *(const short8*)(A2 + kk * 32);
    }

    #pragma unroll
    for (int jt = 0; jt < 2; ++jt) {
        const int j0 = (w * 2 + jt) * 16;
        const size_t boff = (size_t)(j0 + lr) * NFEAT + kh * 8;
        const short* Bir = (const short*)wihb + boff;
        const short* Biz = Bir + 256 * NFEAT;
        const short* Bin = Bir + 512 * NFEAT;
        const short* Bhr = (const short*)whhb + boff;
        const short* Bhz = Bhr + 256 * NFEAT;
        const short* Bhn = Bhr + 512 * NFEAT;

        floatx4 air = {0,0,0,0}, aiz = {0,0,0,0}, ain = {0,0,0,0};
        floatx4 ahr = {0,0,0,0}, ahz = {0,0,0,0}, ahn = {0,0,0,0};
        #pragma unroll
        for (int kk = 0; kk < 8; ++kk) {
            const int k = kk * 32;
            air = __builtin_amdgcn_mfma_f32_16x16x32_bf16(a1[kk], *(const short8*)(Bir + k), air, 0, 0, 0);
            aiz = __builtin_amdgcn_mfma_f32_16x16x32_bf16(a1[kk], *(const short8*)(Biz + k), aiz, 0, 0, 0);
            ain = __builtin_amdgcn_mfma_f32_16x16x32_bf16(a1[kk], *(const short8*)(Bin + k), ain, 0, 0, 0);
            ahr = __builtin_amdgcn_mfma_f32_16x16x32_bf16(a2[kk], *(const short8*)(Bhr + k), ahr, 0, 0, 0);
            ahz = __builtin_amdgcn_mfma_f32_16x16x32_bf16(a2[kk], *(const short8*)(Bhz + k), ahz, 0, 0, 0);
            ahn = __builtin_amdgcn_mfma_f32_16x16x32_bf16(a2[kk], *(const short8*)(Bhn + k), ahn, 0, 0, 0);
        }
        const int col = j0 + lr;
        const float b_ir = bih[col], b_iz = bih[256 + col], b_in = bih[512 + col];
        const float b_hr = bhh[col], b_hz = bhh[256 + col], b_hn = bhh[512 + col];
        #pragma unroll
        for (int r = 0; r < 4; ++r) {
            int row = m0 + kh * 4 + r;
            float rg = sigmoidf_((air[r] + b_ir) + (ahr[r] + b_hr));
            float ug = sigmoidf_((aiz[r] + b_iz) + (ahz[r] + b_hz));
            float ng = tanhf((ain[r] + b_in) + rg * (ahn[r] + b_hn));
            float h  = gf[(size_t)row * NFEAT + col];   // fp32 hidden state
            out[(size_t)row * NFEAT + col] = (1.0f - ug) * ng + ug * h;
        }
    }
}

extern "C" void kernel_launch(void* const* d_in, const int* in_sizes, int n_in,
                              void* d_out, int out_size, void* d_ws, size_t ws_size,
                              hipStream_t stream)
{
    const float* nf  = (const float*)d_in[0];   // node_feats [V,256] fp32
    const float* gf  = (const float*)d_in[1];   // g_feats   [G,256] fp32
    const int*   seg = (const int*)d_in[2];     // segment_ids [V], sorted
    const float* Wl  = (const float*)d_in[3];   // [1,512]
    const float* bl  = (const float*)d_in[4];   // [1]
    const float* Wp  = (const float*)d_in[5];   // [256,256]
    const float* bp  = (const float*)d_in[6];   // [256]
    const float* Wih = (const float*)d_in[7];   // [768,256]
    const float* Whh = (const float*)d_in[8];   // [768,256]
    const float* bih = (const float*)d_in[9];   // [768]
    const float* bhh = (const float*)d_in[10];  // [768]

    const int V = in_sizes[2];
    const int G = in_sizes[1] / NFEAT;

    // workspace layout (16B-aligned regions)
    char* ws = (char*)d_ws;
    u16*   sbuf = (u16*)ws;                           ws += (size_t)G * NFEAT * 2;  // 2 MB
    u16*   gfb  = (u16*)ws;                           ws += (size_t)G * NFEAT * 2;  // 2 MB
    u16*   wpb  = (u16*)ws;                           ws += (size_t)256 * 256 * 2;  // 128 KB
    u16*   wihb = (u16*)ws;                           ws += (size_t)768 * 256 * 2;  // 384 KB
    u16*   whhb = (u16*)ws;                           ws += (size_t)768 * 256 * 2;  // 384 KB
    float* pres = (float*)ws;                         ws += (size_t)G * 4;          // 16 KB

    k1_attn_pool<<<G, 256, 0, stream>>>(nf, gf, seg, V, G, Wl, bl,
                                        Wp, Wih, Whh,
                                        sbuf, pres, gfb, wpb, wihb, whhb);
    k2_fused<<<G / 16, 512, 0, stream>>>(sbuf, wpb, bp, pres, gfb, gf,
                                         wihb, whhb, bih, bhh, (float*)d_out);
    (void)ws_size; (void)n_in; (void)out_size;
}